// Round 4
// baseline (616.775 us; speedup 1.0000x reference)
//
#include <hip/hip_runtime.h>

typedef _Float16 half8 __attribute__((ext_vector_type(8)));
typedef short short8 __attribute__((ext_vector_type(8)));
typedef float floatx4 __attribute__((ext_vector_type(4)));

#define GLDS16(g, l) __builtin_amdgcn_global_load_lds( \
    (const __attribute__((address_space(1))) unsigned int*)(g), \
    (__attribute__((address_space(3))) unsigned int*)(l), 16, 0, 0)

static __device__ __forceinline__ short f2bf(float f){
  union { float f; unsigned u; } v; v.f = f;
  unsigned r = v.u + 0x7fffu + ((v.u >> 16) & 1u);
  return (short)(r >> 16);
}
static __device__ __forceinline__ float bf2f(short s){
  union { unsigned u; float f; } v; v.u = ((unsigned)(unsigned short)s) << 16;
  return v.f;
}
static __device__ __forceinline__ float redmax16(float v){
  v = fmaxf(v, __shfl_xor(v, 1));
  v = fmaxf(v, __shfl_xor(v, 2));
  v = fmaxf(v, __shfl_xor(v, 4));
  v = fmaxf(v, __shfl_xor(v, 8));
  return v;
}
static __device__ __forceinline__ float redsum16(float v){
  v += __shfl_xor(v, 1);
  v += __shfl_xor(v, 2);
  v += __shfl_xor(v, 4);
  v += __shfl_xor(v, 8);
  return v;
}

// ---- X/M fp32 -> fragment-major bf16 hi/lo.  Frag layout: [kt(32)][ntile(256)][64][8]
__global__ __launch_bounds__(256) void kconvA(const float* __restrict__ X,
                                              const float* __restrict__ Mm,
                                              short* __restrict__ XFh, short* __restrict__ XFl,
                                              short* __restrict__ MFh, short* __restrict__ MFl){
  int b = blockIdx.x;                       // 512: src=b>>8, ntile=b&255
  int t = threadIdx.x, w = t >> 6, l = t & 63, quad = l >> 4;
  int srcsel = b >> 8, ntile = b & 255;
  const float* A = srcsel ? Mm : X;
  short* oh = srcsel ? MFh : XFh;
  short* ol = srcsel ? MFl : XFl;
  int row = ntile*16 + (l & 15);
  #pragma unroll
  for (int i = 0; i < 8; i++){
    int kt = w*8 + i;
    const float* p = A + (size_t)row*1024 + kt*32 + quad*8;
    float4 v0 = *(const float4*)p, v1 = *(const float4*)(p + 4);
    float vv[8] = {v0.x,v0.y,v0.z,v0.w,v1.x,v1.y,v1.z,v1.w};
    short8 hh, ll;
    #pragma unroll
    for (int j = 0; j < 8; j++){
      short hb = f2bf(vv[j]); hh[j] = hb; ll[j] = f2bf(vv[j] - bf2f(hb));
    }
    size_t off = ((size_t)kt*256 + ntile)*512 + l*8;
    *(short8*)&oh[off] = hh;
    *(short8*)&ol[off] = ll;
  }
}

// ---- Wq/Wk/Wv fp32 [h][1024][64] -> fragment-major bf16 hi/lo [mat*16+h][kt(32)][ftile(4)][64][8]
__global__ __launch_bounds__(256) void kconvW(const float* __restrict__ Wq,
                                              const float* __restrict__ Wk,
                                              const float* __restrict__ Wv,
                                              short* __restrict__ WFh, short* __restrict__ WFl){
  int bidx = blockIdx.x;                    // 48
  int mat = bidx >> 4, h = bidx & 15;
  const float* W = (mat == 0 ? Wq : (mat == 1 ? Wk : Wv)) + (size_t)h*65536;
  int t = threadIdx.x, w = t >> 6, l = t & 63, quad = l >> 4, fl = l & 15;
  int ftile = w;
  for (int kt = 0; kt < 32; kt++){
    short8 hh, ll;
    #pragma unroll
    for (int j = 0; j < 8; j++){
      float v = W[(size_t)(kt*32 + quad*8 + j)*64 + ftile*16 + fl];
      short hb = f2bf(v); hh[j] = hb; ll[j] = f2bf(v - bf2f(hb));
    }
    size_t frag = ((size_t)bidx*32 + kt)*4 + ftile;
    *(short8*)&WFh[frag*512 + l*8] = hh;
    *(short8*)&WFl[frag*512 + l*8] = ll;
  }
}

// ---- mask -> transposed bitmask: bit b of bitsT[m*128 + nw] = mask[nw*32+b][m]
__global__ __launch_bounds__(256) void kmaskpackT(const int* __restrict__ mask,
                                                  unsigned* __restrict__ bitsT){
  int t = threadIdx.x, w = t >> 6, l = t & 63;
  int wid = blockIdx.x*4 + w;               // 4096 waves
  int n0 = (wid & 63)*64, ms = (wid >> 6)*64;
  for (int mi = 0; mi < 64; mi++){
    int m = ms + mi;
    int v = mask[(size_t)(n0 + l)*4096 + m];
    unsigned long long b = __ballot(v != 0);
    if (l == 0) *(unsigned long long*)(bitsT + (size_t)m*128 + (n0 >> 5)) = b;
  }
}

// ---- fp32 [R][C] (z-batch) -> transposed bf16 hi/lo [C][R]  (for Wo)
__global__ __launch_bounds__(256) void ktransw(const float* __restrict__ src,
                                               short* __restrict__ dsth,
                                               short* __restrict__ dstl,
                                               int R, int C){
  __shared__ float tile[32][33];
  size_t boff = (size_t)blockIdx.z * R * C;
  src += boff; dsth += boff; dstl += boff;
  int r0 = blockIdx.y*32, c0 = blockIdx.x*32;
  int t = threadIdx.x, tr = t >> 3, tc = (t & 7)*4;
  const float* s = src + (size_t)(r0 + tr)*C + c0 + tc;
  #pragma unroll
  for (int i = 0; i < 4; i++) tile[tr][tc + i] = s[i];
  __syncthreads();
  short* dh = dsth + (size_t)(c0 + tr)*R + r0 + tc;
  short* dl = dstl + (size_t)(c0 + tr)*R + r0 + tc;
  #pragma unroll
  for (int i = 0; i < 4; i++){
    float v = tile[tc + i][tr];
    short hb = f2bf(v);
    dh[i] = hb; dl[i] = f2bf(v - bf2f(hb));
  }
}

// ---- QKV projection: fragment-major in, fragment-major out (Q/K f16 hi/lo, V f16)
__global__ __launch_bounds__(256,2) void kproj2(
    const short* __restrict__ XFh, const short* __restrict__ XFl,
    const short* __restrict__ MFh, const short* __restrict__ MFl,
    const short* __restrict__ WFh, const short* __restrict__ WFl,
    _Float16* __restrict__ QFh, _Float16* __restrict__ QFl,
    _Float16* __restrict__ KFh, _Float16* __restrict__ KFl,
    _Float16* __restrict__ VF)
{
  __shared__ short AhL[4096], AlL[4096], BhL[2048], BlL[2048];
  int cb = blockIdx.x, rb = blockIdx.y;
  int mat = cb >> 4, h = cb & 15;
  const short* Ah = (mat == 0) ? XFh : MFh;
  const short* Al = (mat == 0) ? XFl : MFl;
  int t = threadIdx.x, w = t >> 6, l = t & 63, quad = l >> 4, ln = l & 15;
  floatx4 acc[2][4] = {};
  for (int kt = 0; kt < 32; kt++){
    __syncthreads();
    size_t abase = ((size_t)kt*256 + rb*8)*512;
    #pragma unroll
    for (int i = 0; i < 2; i++){
      int cidx = i*256 + t;
      GLDS16(Ah + abase + cidx*8, &AhL[(i*256 + w*64)*8]);
      GLDS16(Al + abase + cidx*8, &AlL[(i*256 + w*64)*8]);
    }
    size_t bbase = (((size_t)cb*32 + kt)*4)*512;
    GLDS16(WFh + bbase + t*8, &BhL[(w*64)*8]);
    GLDS16(WFl + bbase + t*8, &BlL[(w*64)*8]);
    __syncthreads();
    short8 bh[4], bl[4];
    #pragma unroll
    for (int nt = 0; nt < 4; nt++){
      bh[nt] = *(short8*)&BhL[nt*512 + l*8];
      bl[nt] = *(short8*)&BlL[nt*512 + l*8];
    }
    #pragma unroll
    for (int mt = 0; mt < 2; mt++){
      short8 ah = *(short8*)&AhL[(w*2 + mt)*512 + l*8];
      short8 al = *(short8*)&AlL[(w*2 + mt)*512 + l*8];
      #pragma unroll
      for (int nt = 0; nt < 4; nt++){
        acc[mt][nt] = __builtin_amdgcn_mfma_f32_16x16x32_bf16(ah, bh[nt], acc[mt][nt], 0, 0, 0);
        acc[mt][nt] = __builtin_amdgcn_mfma_f32_16x16x32_bf16(ah, bl[nt], acc[mt][nt], 0, 0, 0);
        acc[mt][nt] = __builtin_amdgcn_mfma_f32_16x16x32_bf16(al, bh[nt], acc[mt][nt], 0, 0, 0);
      }
    }
  }
  int row0 = rb*128;
  #pragma unroll
  for (int mt = 0; mt < 2; mt++)
    #pragma unroll
    for (int nt = 0; nt < 4; nt++)
      #pragma unroll
      for (int rg = 0; rg < 4; rg++){
        int n = row0 + w*32 + mt*16 + quad*4 + rg;
        int c = nt*16 + ln;
        float v = acc[mt][nt][rg];
        if (mat == 2){
          int lane2 = ln + (((n >> 3) & 3) << 4);
          VF[(((size_t)h*128 + (n >> 5))*4 + nt)*512 + lane2*8 + (n & 7)] = (_Float16)v;
        } else {
          _Float16 hi = (_Float16)v;
          _Float16 lo = (_Float16)(v - (float)hi);
          int lane2 = (n & 15) + (((c >> 3) & 3) << 4);
          size_t off = (((size_t)h*256 + (n >> 4))*2 + (c >> 5))*512 + lane2*8 + (c & 7);
          if (mat == 0){ QFh[off] = hi; QFl[off] = lo; }
          else         { KFh[off] = hi; KFl[off] = lo; }
        }
      }
}

// ---- flash attention: 512 blocks (h, 128-row q-tile), BN=128, fragment LDS, 2 barriers/iter
__global__ __launch_bounds__(256,2) void kattn2(
    const _Float16* __restrict__ QFh, const _Float16* __restrict__ QFl,
    const _Float16* __restrict__ KFh, const _Float16* __restrict__ KFl,
    const _Float16* __restrict__ VF, const unsigned* __restrict__ bitsT,
    short* __restrict__ Ows)
{
  __shared__ _Float16 KBh[8192], KBl[8192], VB[8192], PB[8192];
  int bx = blockIdx.x, h = bx & 15, qb = bx >> 4, q0 = qb*128;
  int t = threadIdx.x, w = t >> 6, l = t & 63, quad = l >> 4, ln = l & 15;

  half8 qh[2][2], ql[2][2];
  #pragma unroll
  for (int mt = 0; mt < 2; mt++)
    #pragma unroll
    for (int kc = 0; kc < 2; kc++){
      size_t off = (((size_t)h*256 + qb*8 + w*2 + mt)*2 + kc)*512 + l*8;
      qh[mt][kc] = *(const half8*)&QFh[off];
      ql[mt][kc] = *(const half8*)&QFl[off];
    }

  floatx4 o[2][4] = {};
  float mst[2][4], lst[2][4];
  #pragma unroll
  for (int mt = 0; mt < 2; mt++)
    #pragma unroll
    for (int rg = 0; rg < 4; rg++){ mst[mt][rg] = -1e30f; lst[mt][rg] = 0.f; }

  for (int kt = 0; kt < 32; kt++){
    __syncthreads();
    size_t kb = (size_t)h*262144 + (size_t)kt*8192;
    #pragma unroll
    for (int i = 0; i < 4; i++){
      int cidx = i*256 + t;
      GLDS16(KFh + kb + cidx*8, &KBh[(i*256 + w*64)*8]);
      GLDS16(KFl + kb + cidx*8, &KBl[(i*256 + w*64)*8]);
      GLDS16(VF  + kb + cidx*8, &VB [(i*256 + w*64)*8]);
    }
    unsigned b0 = bitsT[((size_t)kt*128 + l)*128 + qb*4 + w];
    unsigned b1 = bitsT[((size_t)kt*128 + 64 + l)*128 + qb*4 + w];
    __syncthreads();

    // S = Qhi*Khi + Qhi*Klo + Qlo*Khi
    floatx4 sa[2][8] = {};
    #pragma unroll
    for (int kc = 0; kc < 2; kc++)
      #pragma unroll
      for (int nt = 0; nt < 8; nt++){
        half8 kh  = *(half8*)&KBh[(nt*2 + kc)*512 + l*8];
        half8 klo = *(half8*)&KBl[(nt*2 + kc)*512 + l*8];
        #pragma unroll
        for (int mt = 0; mt < 2; mt++){
          sa[mt][nt] = __builtin_amdgcn_mfma_f32_16x16x32_f16(qh[mt][kc], kh,  sa[mt][nt], 0, 0, 0);
          sa[mt][nt] = __builtin_amdgcn_mfma_f32_16x16x32_f16(qh[mt][kc], klo, sa[mt][nt], 0, 0, 0);
          sa[mt][nt] = __builtin_amdgcn_mfma_f32_16x16x32_f16(ql[mt][kc], kh,  sa[mt][nt], 0, 0, 0);
        }
      }

    // mask (transposed bits, one word per column, bit = row-in-32)
    #pragma unroll
    for (int nt = 0; nt < 8; nt++){
      unsigned wm = (unsigned)__shfl((int)(nt < 4 ? b0 : b1), (nt & 3)*16 + ln);
      #pragma unroll
      for (int mt = 0; mt < 2; mt++)
        #pragma unroll
        for (int rg = 0; rg < 4; rg++)
          if (!((wm >> (mt*16 + quad*4 + rg)) & 1u)) sa[mt][nt][rg] = -1e30f;
    }

    // online softmax stats over the 128-col chunk
    #pragma unroll
    for (int mt = 0; mt < 2; mt++)
      #pragma unroll
      for (int rg = 0; rg < 4; rg++){
        float mx = sa[mt][0][rg];
        #pragma unroll
        for (int nt = 1; nt < 8; nt++) mx = fmaxf(mx, sa[mt][nt][rg]);
        mx = redmax16(mx);
        float mnew = fmaxf(mst[mt][rg], mx);
        float alpha = __expf(mst[mt][rg] - mnew);
        mst[mt][rg] = mnew;
        lst[mt][rg] *= alpha;
        #pragma unroll
        for (int vt = 0; vt < 4; vt++) o[mt][vt][rg] *= alpha;
        float s = 0.f;
        #pragma unroll
        for (int nt = 0; nt < 8; nt++){
          float p = __expf(sa[mt][nt][rg] - mnew);
          sa[mt][nt][rg] = p;
          s += p;
        }
        lst[mt][rg] += redsum16(s);
      }

    // P halves -> per-wave LDS A-fragments -> PV
    #pragma unroll
    for (int hf = 0; hf < 2; hf++){
      #pragma unroll
      for (int nt4 = 0; nt4 < 4; nt4++){
        int nt = hf*4 + nt4;
        int ncl = nt4 >> 1;
        int base = w*2048 + ncl*512 + ((quad*4) + (((nt*2 + (ln >> 3)) & 3) << 4))*8 + (ln & 7);
        #pragma unroll
        for (int mt = 0; mt < 2; mt++)
          #pragma unroll
          for (int rg = 0; rg < 4; rg++)
            PB[base + mt*1024 + rg*8] = (_Float16)sa[mt][nt][rg];
      }
      #pragma unroll
      for (int ncl = 0; ncl < 2; ncl++){
        half8 pf0 = *(half8*)&PB[w*2048 + ncl*512 + l*8];
        half8 pf1 = *(half8*)&PB[w*2048 + 1024 + ncl*512 + l*8];
        #pragma unroll
        for (int vt = 0; vt < 4; vt++){
          half8 vf = *(half8*)&VB[(((hf*2 + ncl)*4) + vt)*512 + l*8];
          o[0][vt] = __builtin_amdgcn_mfma_f32_16x16x32_f16(pf0, vf, o[0][vt], 0, 0, 0);
          o[1][vt] = __builtin_amdgcn_mfma_f32_16x16x32_f16(pf1, vf, o[1][vt], 0, 0, 0);
        }
      }
    }
  }

  #pragma unroll
  for (int mt = 0; mt < 2; mt++)
    #pragma unroll
    for (int rg = 0; rg < 4; rg++){
      float li = lst[mt][rg];
      float inv = (li > 0.f) ? (1.f / li) : 0.f;
      int n = q0 + w*32 + mt*16 + quad*4 + rg;
      #pragma unroll
      for (int vt = 0; vt < 4; vt++)
        Ows[(size_t)n*1024 + h*64 + vt*16 + ln] = f2bf(o[mt][vt][rg]*inv);
    }
}

// ---- Y[f32] = O[4096x1024 bf16] @ Wot[1024x1024 bf16 B^T rows]
__global__ __launch_bounds__(256,2) void kfinal(const short* __restrict__ Ain,
                                                const short* __restrict__ Bt,
                                                float* __restrict__ Y)
{
  __shared__ short Al[128*48];
  __shared__ short Bl[64*48];
  int cb = blockIdx.x, rb = blockIdx.y;
  int row0 = rb*128, col0 = cb*64;
  int t = threadIdx.x, w = t >> 6, l = t & 63, quad = l >> 4, ln = l & 15;
  floatx4 acc[2][4] = {};
  for (int d0 = 0; d0 < 1024; d0 += 32){
    #pragma unroll
    for (int i = 0; i < 2; i++){
      int u = t + i*256, r = u >> 2, s = u & 3;
      *(int4*)&Al[r*48 + s*8] = *(const int4*)&Ain[(size_t)(row0 + r)*1024 + d0 + s*8];
    }
    { int r = t >> 2, s = t & 3;
      *(int4*)&Bl[r*48 + s*8] = *(const int4*)&Bt[(size_t)(col0 + r)*1024 + d0 + s*8]; }
    __syncthreads();
    short8 bf[4];
    #pragma unroll
    for (int nt = 0; nt < 4; nt++) bf[nt] = *(short8*)&Bl[(nt*16 + ln)*48 + quad*8];
    #pragma unroll
    for (int mt = 0; mt < 2; mt++){
      short8 af = *(short8*)&Al[(w*32 + mt*16 + ln)*48 + quad*8];
      #pragma unroll
      for (int nt = 0; nt < 4; nt++)
        acc[mt][nt] = __builtin_amdgcn_mfma_f32_16x16x32_bf16(af, bf[nt], acc[mt][nt], 0, 0, 0);
    }
    __syncthreads();
  }
  #pragma unroll
  for (int mt = 0; mt < 2; mt++)
    #pragma unroll
    for (int nt = 0; nt < 4; nt++)
      #pragma unroll
      for (int rg = 0; rg < 4; rg++){
        int n = row0 + w*32 + mt*16 + quad*4 + rg;
        int c = col0 + nt*16 + ln;
        Y[(size_t)n*1024 + c] = acc[mt][nt][rg];
      }
}

extern "C" void kernel_launch(void* const* d_in, const int* in_sizes, int n_in,
                              void* d_out, int out_size, void* d_ws, size_t ws_size,
                              hipStream_t stream){
  (void)in_sizes; (void)n_in; (void)out_size; (void)ws_size;
  const float* X    = (const float*)d_in[0];
  const float* Mm   = (const float*)d_in[1];
  const int*   mask = (const int*)d_in[2];
  const float* Wq   = (const float*)d_in[3];
  const float* Wk   = (const float*)d_in[4];
  const float* Wv   = (const float*)d_in[5];
  const float* Wo   = (const float*)d_in[6];
  float* Y = (float*)d_out;
  char* ws = (char*)d_ws;
  const size_t MB = 1024*1024;
  short*    XFh   = (short*)   (ws +  0*MB);   // dead after kproj2; Ows reuses
  short*    XFl   = (short*)   (ws +  8*MB);   // dead after kproj2; Wot/Wotl reuse
  short*    MFh   = (short*)   (ws + 16*MB);
  short*    MFl   = (short*)   (ws + 24*MB);
  short*    WFh   = (short*)   (ws + 32*MB);   // 6MB
  short*    WFl   = (short*)   (ws + 38*MB);   // 6MB
  unsigned* bitsT = (unsigned*)(ws + 44*MB);   // 2MB
  _Float16* QFh   = (_Float16*)(ws + 46*MB);
  _Float16* QFl   = (_Float16*)(ws + 54*MB);
  _Float16* KFh   = (_Float16*)(ws + 62*MB);
  _Float16* KFl   = (_Float16*)(ws + 70*MB);
  _Float16* VF    = (_Float16*)(ws + 78*MB);
  short*    Ows   = (short*)   (ws +  0*MB);   // alias XFh (after kproj2)
  short*    Wot   = (short*)   (ws +  8*MB);   // alias XFl (after kproj2)
  short*    Wotl  = (short*)   (ws + 10*MB);

  kconvA<<<512, 256, 0, stream>>>(X, Mm, XFh, XFl, MFh, MFl);
  kconvW<<<48, 256, 0, stream>>>(Wq, Wk, Wv, WFh, WFl);
  kmaskpackT<<<1024, 256, 0, stream>>>(mask, bitsT);
  kproj2<<<dim3(48,32), 256, 0, stream>>>(XFh, XFl, MFh, MFl, WFh, WFl,
                                          QFh, QFl, KFh, KFl, VF);
  ktransw<<<dim3(32,32,1), 256, 0, stream>>>(Wo, Wot, Wotl, 1024, 1024);
  kattn2<<<512, 256, 0, stream>>>(QFh, QFl, KFh, KFl, VF, bitsT, Ows);
  kfinal<<<dim3(16,32), 256, 0, stream>>>(Ows, Wot, Y);
}

// Round 5
// 486.647 us; speedup vs baseline: 1.2674x; 1.2674x over previous
//
#include <hip/hip_runtime.h>

typedef _Float16 half8 __attribute__((ext_vector_type(8)));
typedef _Float16 half2v __attribute__((ext_vector_type(2)));
typedef short short8 __attribute__((ext_vector_type(8)));
typedef short short4v __attribute__((ext_vector_type(4)));
typedef float floatx4 __attribute__((ext_vector_type(4)));

#define GLDS16(g, l) __builtin_amdgcn_global_load_lds( \
    (const __attribute__((address_space(1))) unsigned int*)(g), \
    (__attribute__((address_space(3))) unsigned int*)(l), 16, 0, 0)

static __device__ __forceinline__ short f2bf(float f){
  union { float f; unsigned u; } v; v.f = f;
  unsigned r = v.u + 0x7fffu + ((v.u >> 16) & 1u);
  return (short)(r >> 16);
}
static __device__ __forceinline__ float bf2f(short s){
  union { unsigned u; float f; } v; v.u = ((unsigned)(unsigned short)s) << 16;
  return v.f;
}

// ---- X/M fp32 -> fragment-major bf16 hi/lo.  Frag layout: [kt(32)][ntile(256)][64][8]
__global__ __launch_bounds__(256) void kconvA(const float* __restrict__ X,
                                              const float* __restrict__ Mm,
                                              short* __restrict__ XFh, short* __restrict__ XFl,
                                              short* __restrict__ MFh, short* __restrict__ MFl){
  int b = blockIdx.x;                       // 512: src=b>>8, ntile=b&255
  int t = threadIdx.x, w = t >> 6, l = t & 63, quad = l >> 4;
  int srcsel = b >> 8, ntile = b & 255;
  const float* A = srcsel ? Mm : X;
  short* oh = srcsel ? MFh : XFh;
  short* ol = srcsel ? MFl : XFl;
  int row = ntile*16 + (l & 15);
  #pragma unroll
  for (int i = 0; i < 8; i++){
    int kt = w*8 + i;
    const float* p = A + (size_t)row*1024 + kt*32 + quad*8;
    float4 v0 = *(const float4*)p, v1 = *(const float4*)(p + 4);
    float vv[8] = {v0.x,v0.y,v0.z,v0.w,v1.x,v1.y,v1.z,v1.w};
    short8 hh, ll;
    #pragma unroll
    for (int j = 0; j < 8; j++){
      short hb = f2bf(vv[j]); hh[j] = hb; ll[j] = f2bf(vv[j] - bf2f(hb));
    }
    size_t off = ((size_t)kt*256 + ntile)*512 + l*8;
    *(short8*)&oh[off] = hh;
    *(short8*)&ol[off] = ll;
  }
}

// ---- Wq/Wk/Wv fp32 [h][1024][64] -> fragment-major bf16 hi/lo, LDS-staged coalesced
__global__ __launch_bounds__(256) void kconvW2(const float* __restrict__ Wq,
                                               const float* __restrict__ Wk,
                                               const float* __restrict__ Wv,
                                               short* __restrict__ WFh, short* __restrict__ WFl){
  __shared__ float T[128][68];
  int bidx = blockIdx.x, g = blockIdx.y;    // bidx 0..47, g 0..7 (4 kt each)
  int mat = bidx >> 4, h = bidx & 15;
  const float* W = (mat == 0 ? Wq : (mat == 1 ? Wk : Wv)) + (size_t)h*65536;
  int t = threadIdx.x, w = t >> 6, l = t & 63, quad = (l >> 4) & 3, fl = l & 15;
  #pragma unroll
  for (int p = 0; p < 32; p++){
    int idx = p*256 + t, row = idx >> 6, col = idx & 63;
    T[row][col] = W[(size_t)(g*128 + row)*64 + col];
  }
  __syncthreads();
  for (int ktl = 0; ktl < 4; ktl++){
    short8 hh, ll;
    #pragma unroll
    for (int j = 0; j < 8; j++){
      float v = T[ktl*32 + quad*8 + j][w*16 + fl];
      short hb = f2bf(v); hh[j] = hb; ll[j] = f2bf(v - bf2f(hb));
    }
    size_t frag = ((size_t)bidx*32 + g*4 + ktl)*4 + w;
    *(short8*)&WFh[frag*512 + l*8] = hh;
    *(short8*)&WFl[frag*512 + l*8] = ll;
  }
}

// ---- mask -> bitmask (row orientation): bits[n*128 + kw] bit i = mask[n][kw*32+i]
__global__ __launch_bounds__(256) void kmaskpack(const int* __restrict__ mask,
                                                 unsigned* __restrict__ bits){
  int w = blockIdx.x * 256 + threadIdx.x;          // 4096*128 words
  const int* p = mask + (size_t)w * 32;
  unsigned b = 0;
  #pragma unroll
  for (int i = 0; i < 32; i++) b |= (p[i] != 0) ? (1u << i) : 0u;
  bits[w] = b;
}

// ---- fp32 [R][C] (z-batch) -> transposed bf16 hi/lo [C][R]  (for Wo)
__global__ __launch_bounds__(256) void ktransw(const float* __restrict__ src,
                                               short* __restrict__ dsth,
                                               short* __restrict__ dstl,
                                               int R, int C){
  __shared__ float tile[32][33];
  size_t boff = (size_t)blockIdx.z * R * C;
  src += boff; dsth += boff; dstl += boff;
  int r0 = blockIdx.y*32, c0 = blockIdx.x*32;
  int t = threadIdx.x, tr = t >> 3, tc = (t & 7)*4;
  const float* s = src + (size_t)(r0 + tr)*C + c0 + tc;
  #pragma unroll
  for (int i = 0; i < 4; i++) tile[tr][tc + i] = s[i];
  __syncthreads();
  short* dh = dsth + (size_t)(c0 + tr)*R + r0 + tc;
  short* dl = dstl + (size_t)(c0 + tr)*R + r0 + tc;
  #pragma unroll
  for (int i = 0; i < 4; i++){
    float v = tile[tc + i][tr];
    short hb = f2bf(v);
    dh[i] = hb; dl[i] = f2bf(v - bf2f(hb));
  }
}

// ---- QKV projection: fragment-major in, fragment-major out (Q/K f16 hi/lo, V f16)
__global__ __launch_bounds__(256,2) void kproj2(
    const short* __restrict__ XFh, const short* __restrict__ XFl,
    const short* __restrict__ MFh, const short* __restrict__ MFl,
    const short* __restrict__ WFh, const short* __restrict__ WFl,
    _Float16* __restrict__ QFh, _Float16* __restrict__ QFl,
    _Float16* __restrict__ KFh, _Float16* __restrict__ KFl,
    _Float16* __restrict__ VF)
{
  __shared__ short AhL[4096], AlL[4096], BhL[2048], BlL[2048];
  int cb = blockIdx.x, rb = blockIdx.y;
  int mat = cb >> 4, h = cb & 15;
  const short* Ah = (mat == 0) ? XFh : MFh;
  const short* Al = (mat == 0) ? XFl : MFl;
  int t = threadIdx.x, w = t >> 6, l = t & 63, quad = l >> 4, ln = l & 15;
  floatx4 acc[2][4] = {};
  for (int kt = 0; kt < 32; kt++){
    __syncthreads();
    size_t abase = ((size_t)kt*256 + rb*8)*512;
    #pragma unroll
    for (int i = 0; i < 2; i++){
      int cidx = i*256 + t;
      GLDS16(Ah + abase + cidx*8, &AhL[(i*256 + w*64)*8]);
      GLDS16(Al + abase + cidx*8, &AlL[(i*256 + w*64)*8]);
    }
    size_t bbase = (((size_t)cb*32 + kt)*4)*512;
    GLDS16(WFh + bbase + t*8, &BhL[(w*64)*8]);
    GLDS16(WFl + bbase + t*8, &BlL[(w*64)*8]);
    __syncthreads();
    short8 bh[4], bl[4];
    #pragma unroll
    for (int nt = 0; nt < 4; nt++){
      bh[nt] = *(short8*)&BhL[nt*512 + l*8];
      bl[nt] = *(short8*)&BlL[nt*512 + l*8];
    }
    #pragma unroll
    for (int mt = 0; mt < 2; mt++){
      short8 ah = *(short8*)&AhL[(w*2 + mt)*512 + l*8];
      short8 al = *(short8*)&AlL[(w*2 + mt)*512 + l*8];
      #pragma unroll
      for (int nt = 0; nt < 4; nt++){
        acc[mt][nt] = __builtin_amdgcn_mfma_f32_16x16x32_bf16(ah, bh[nt], acc[mt][nt], 0, 0, 0);
        acc[mt][nt] = __builtin_amdgcn_mfma_f32_16x16x32_bf16(ah, bl[nt], acc[mt][nt], 0, 0, 0);
        acc[mt][nt] = __builtin_amdgcn_mfma_f32_16x16x32_bf16(al, bh[nt], acc[mt][nt], 0, 0, 0);
      }
    }
  }
  int row0 = rb*128;
  #pragma unroll
  for (int mt = 0; mt < 2; mt++)
    #pragma unroll
    for (int nt = 0; nt < 4; nt++)
      #pragma unroll
      for (int rg = 0; rg < 4; rg++){
        int n = row0 + w*32 + mt*16 + quad*4 + rg;
        int c = nt*16 + ln;
        float v = acc[mt][nt][rg];
        if (mat == 2){
          int lane2 = ln + (((n >> 3) & 3) << 4);
          VF[(((size_t)h*128 + (n >> 5))*4 + nt)*512 + lane2*8 + (n & 7)] = (_Float16)v;
        } else {
          _Float16 hi = (_Float16)v;
          _Float16 lo = (_Float16)(v - (float)hi);
          int lane2 = (n & 15) + (((c >> 3) & 3) << 4);
          size_t off = (((size_t)h*256 + (n >> 4))*2 + (c >> 5))*512 + lane2*8 + (c & 7);
          if (mat == 0){ QFh[off] = hi; QFl[off] = lo; }
          else         { KFh[off] = hi; KFl[off] = lo; }
        }
      }
}

// ---- flash attention v3: S^T = K*Q^T (2 shfl/row-chain), P->PV via packed b32 scratch
__global__ __launch_bounds__(256,3) void kattn3(
    const _Float16* __restrict__ QFh, const _Float16* __restrict__ QFl,
    const _Float16* __restrict__ KFh, const _Float16* __restrict__ KFl,
    const _Float16* __restrict__ VF, const unsigned* __restrict__ bits,
    short* __restrict__ Ows)
{
  __shared__ _Float16 KBh[8192], KBl[8192], VB[8192];
  __shared__ _Float16 Pscr[4][16][40];          // per-wave 16 q-rows x (32 k + 8 pad)
  int bx = blockIdx.x, h = bx & 15, qb = bx >> 4, q0 = qb*128;
  int t = threadIdx.x, w = t >> 6, l = t & 63, quad = l >> 4, ln = l & 15;

  // Q as B-fragments (lane: q=ln, d=quad*8+j per 32-d chunk) — layout identical to A-frag store
  half8 qh[2][2], ql[2][2];
  #pragma unroll
  for (int nt2 = 0; nt2 < 2; nt2++)
    #pragma unroll
    for (int kc = 0; kc < 2; kc++){
      size_t off = (((size_t)h*256 + qb*8 + w*2 + nt2)*2 + kc)*512 + l*8;
      qh[nt2][kc] = *(const half8*)&QFh[off];
      ql[nt2][kc] = *(const half8*)&QFl[off];
    }

  floatx4 o[2][4] = {};                         // O^T: D[v][q], lane: q=ln, v=vt*16+quad*4+rg
  float mst[2] = {-1e30f, -1e30f}, lst[2] = {0.f, 0.f};

  for (int kt = 0; kt < 32; kt++){
    __syncthreads();
    size_t kb = (size_t)h*262144 + (size_t)kt*8192;
    #pragma unroll
    for (int i = 0; i < 4; i++){
      int cidx = i*256 + t;
      GLDS16(KFh + kb + cidx*8, &KBh[(i*256 + w*64)*8]);
      GLDS16(KFl + kb + cidx*8, &KBl[(i*256 + w*64)*8]);
      GLDS16(VF  + kb + cidx*8, &VB [(i*256 + w*64)*8]);
    }
    uint4 mw[2];
    mw[0] = *(const uint4*)&bits[(size_t)(q0 + w*32 + ln)*128 + kt*4];
    mw[1] = *(const uint4*)&bits[(size_t)(q0 + w*32 + 16 + ln)*128 + kt*4];
    __syncthreads();

    // S^T = Khi*Qhi + Klo*Qhi + Khi*Qlo ; each K-frag read once (nt2 inner)
    floatx4 st[2][8] = {};
    #pragma unroll
    for (int kc = 0; kc < 2; kc++)
      #pragma unroll
      for (int m8 = 0; m8 < 8; m8++){
        half8 kh = *(half8*)&KBh[(m8*2 + kc)*512 + l*8];
        half8 kl = *(half8*)&KBl[(m8*2 + kc)*512 + l*8];
        #pragma unroll
        for (int nt2 = 0; nt2 < 2; nt2++){
          st[nt2][m8] = __builtin_amdgcn_mfma_f32_16x16x32_f16(kh, qh[nt2][kc], st[nt2][m8], 0, 0, 0);
          st[nt2][m8] = __builtin_amdgcn_mfma_f32_16x16x32_f16(kl, qh[nt2][kc], st[nt2][m8], 0, 0, 0);
          st[nt2][m8] = __builtin_amdgcn_mfma_f32_16x16x32_f16(kh, ql[nt2][kc], st[nt2][m8], 0, 0, 0);
        }
      }

    #pragma unroll
    for (int nt2 = 0; nt2 < 2; nt2++){
      // mask: lane's q row-word; element (q=ln, k=kt*128 + m8*16 + quad*4 + rg)
      const unsigned* mwp = (const unsigned*)&mw[nt2];
      #pragma unroll
      for (int m8 = 0; m8 < 8; m8++){
        unsigned nib = mwp[m8 >> 1] >> ((m8 & 1)*16 + quad*4);
        #pragma unroll
        for (int rg = 0; rg < 4; rg++)
          if (!((nib >> rg) & 1u)) st[nt2][m8][rg] = -1e30f;
      }
      // row softmax: 32 in-reg + cross-quad (xor 16, 32)
      float mx = st[nt2][0][0];
      #pragma unroll
      for (int m8 = 0; m8 < 8; m8++)
        #pragma unroll
        for (int rg = 0; rg < 4; rg++) mx = fmaxf(mx, st[nt2][m8][rg]);
      mx = fmaxf(mx, __shfl_xor(mx, 16));
      mx = fmaxf(mx, __shfl_xor(mx, 32));
      float mnew = fmaxf(mst[nt2], mx);
      float alpha = __expf(mst[nt2] - mnew);
      mst[nt2] = mnew;
      lst[nt2] *= alpha;
      #pragma unroll
      for (int vt = 0; vt < 4; vt++) o[nt2][vt] *= alpha;
      float s = 0.f;
      #pragma unroll
      for (int m8 = 0; m8 < 8; m8++)
        #pragma unroll
        for (int rg = 0; rg < 4; rg++){
          float p = __expf(st[nt2][m8][rg] - mnew);
          st[nt2][m8][rg] = p; s += p;
        }
      s += __shfl_xor(s, 16);
      s += __shfl_xor(s, 32);
      lst[nt2] += s;

      // PV per 32-k chunk: packed b32 P writes (same-wave scratch, no barrier)
      #pragma unroll
      for (int c = 0; c < 4; c++){
        #pragma unroll
        for (int tt = 0; tt < 2; tt++){
          int m8 = c*2 + tt;
          half2v p01, p23;
          p01[0] = (_Float16)st[nt2][m8][0]; p01[1] = (_Float16)st[nt2][m8][1];
          p23[0] = (_Float16)st[nt2][m8][2]; p23[1] = (_Float16)st[nt2][m8][3];
          *(half2v*)&Pscr[w][ln][tt*16 + quad*4]     = p01;
          *(half2v*)&Pscr[w][ln][tt*16 + quad*4 + 2] = p23;
        }
        half8 pf = *(half8*)&Pscr[w][ln][quad*8];
        #pragma unroll
        for (int vt = 0; vt < 4; vt++){
          half8 vf = *(half8*)&VB[(c*4 + vt)*512 + l*8];
          o[nt2][vt] = __builtin_amdgcn_mfma_f32_16x16x32_f16(vf, pf, o[nt2][vt], 0, 0, 0);
        }
      }
    }
  }

  // epilogue: O^T D-layout -> Ows[n][h*64+v], 4 consecutive v packed per 8B store
  #pragma unroll
  for (int nt2 = 0; nt2 < 2; nt2++){
    float inv = (lst[nt2] > 0.f) ? (1.f / lst[nt2]) : 0.f;
    int n = q0 + w*32 + nt2*16 + ln;
    #pragma unroll
    for (int vt = 0; vt < 4; vt++){
      short4v pk;
      #pragma unroll
      for (int rg = 0; rg < 4; rg++) pk[rg] = f2bf(o[nt2][vt][rg]*inv);
      *(short4v*)&Ows[(size_t)n*1024 + h*64 + vt*16 + quad*4] = pk;
    }
  }
}

// ---- Y[f32] = O[4096x1024 bf16] @ Wot[1024x1024 bf16 B^T rows]
__global__ __launch_bounds__(256,2) void kfinal(const short* __restrict__ Ain,
                                                const short* __restrict__ Bt,
                                                float* __restrict__ Y)
{
  __shared__ short Al[128*48];
  __shared__ short Bl[64*48];
  int cb = blockIdx.x, rb = blockIdx.y;
  int row0 = rb*128, col0 = cb*64;
  int t = threadIdx.x, w = t >> 6, l = t & 63, quad = l >> 4, ln = l & 15;
  floatx4 acc[2][4] = {};
  for (int d0 = 0; d0 < 1024; d0 += 32){
    #pragma unroll
    for (int i = 0; i < 2; i++){
      int u = t + i*256, r = u >> 2, s = u & 3;
      *(int4*)&Al[r*48 + s*8] = *(const int4*)&Ain[(size_t)(row0 + r)*1024 + d0 + s*8];
    }
    { int r = t >> 2, s = t & 3;
      *(int4*)&Bl[r*48 + s*8] = *(const int4*)&Bt[(size_t)(col0 + r)*1024 + d0 + s*8]; }
    __syncthreads();
    short8 bf[4];
    #pragma unroll
    for (int nt = 0; nt < 4; nt++) bf[nt] = *(short8*)&Bl[(nt*16 + ln)*48 + quad*8];
    #pragma unroll
    for (int mt = 0; mt < 2; mt++){
      short8 af = *(short8*)&Al[(w*32 + mt*16 + ln)*48 + quad*8];
      #pragma unroll
      for (int nt = 0; nt < 4; nt++)
        acc[mt][nt] = __builtin_amdgcn_mfma_f32_16x16x32_bf16(af, bf[nt], acc[mt][nt], 0, 0, 0);
    }
    __syncthreads();
  }
  #pragma unroll
  for (int mt = 0; mt < 2; mt++)
    #pragma unroll
    for (int nt = 0; nt < 4; nt++)
      #pragma unroll
      for (int rg = 0; rg < 4; rg++){
        int n = row0 + w*32 + mt*16 + quad*4 + rg;
        int c = col0 + nt*16 + ln;
        Y[(size_t)n*1024 + c] = acc[mt][nt][rg];
      }
}

extern "C" void kernel_launch(void* const* d_in, const int* in_sizes, int n_in,
                              void* d_out, int out_size, void* d_ws, size_t ws_size,
                              hipStream_t stream){
  (void)in_sizes; (void)n_in; (void)out_size; (void)ws_size;
  const float* X    = (const float*)d_in[0];
  const float* Mm   = (const float*)d_in[1];
  const int*   mask = (const int*)d_in[2];
  const float* Wq   = (const float*)d_in[3];
  const float* Wk   = (const float*)d_in[4];
  const float* Wv   = (const float*)d_in[5];
  const float* Wo   = (const float*)d_in[6];
  float* Y = (float*)d_out;
  char* ws = (char*)d_ws;
  const size_t MB = 1024*1024;
  short*    XFh   = (short*)   (ws +  0*MB);   // dead after kproj2; Ows reuses
  short*    XFl   = (short*)   (ws +  8*MB);   // dead after kproj2; Wot/Wotl reuse
  short*    MFh   = (short*)   (ws + 16*MB);
  short*    MFl   = (short*)   (ws + 24*MB);
  short*    WFh   = (short*)   (ws + 32*MB);   // 6MB
  short*    WFl   = (short*)   (ws + 38*MB);   // 6MB
  unsigned* bits  = (unsigned*)(ws + 44*MB);   // 2MB  [4096 n][128 kw]
  _Float16* QFh   = (_Float16*)(ws + 46*MB);
  _Float16* QFl   = (_Float16*)(ws + 54*MB);
  _Float16* KFh   = (_Float16*)(ws + 62*MB);
  _Float16* KFl   = (_Float16*)(ws + 70*MB);
  _Float16* VF    = (_Float16*)(ws + 78*MB);
  short*    Ows   = (short*)   (ws +  0*MB);   // alias XFh (after kproj2)
  short*    Wot   = (short*)   (ws +  8*MB);   // alias XFl (after kproj2)
  short*    Wotl  = (short*)   (ws + 10*MB);

  kconvA<<<512, 256, 0, stream>>>(X, Mm, XFh, XFl, MFh, MFl);
  kconvW2<<<dim3(48,8), 256, 0, stream>>>(Wq, Wk, Wv, WFh, WFl);
  kmaskpack<<<2048, 256, 0, stream>>>(mask, bits);
  kproj2<<<dim3(48,32), 256, 0, stream>>>(XFh, XFl, MFh, MFl, WFh, WFl,
                                          QFh, QFl, KFh, KFl, VF);
  ktransw<<<dim3(32,32,1), 256, 0, stream>>>(Wo, Wot, Wotl, 1024, 1024);
  kattn3<<<512, 256, 0, stream>>>(QFh, QFl, KFh, KFl, VF, bits, Ows);
  kfinal<<<dim3(16,32), 256, 0, stream>>>(Ows, Wot, Y);
}